// Round 19
// baseline (405.525 us; speedup 1.0000x reference)
//
#include <hip/hip_runtime.h>
#include <hip/hip_bf16.h>
#include <cstdint>
#include <cstddef>

#define F_IN 1024
#define F1 64
#define H1 8
#define C1 8
#define C_OUT 40
#define XW2S 64         // padded xw2 row stride (bf16) -> 128 B lines; byte 80 holds alS fp32
#define NEG 0.2f
#define LOG2E 1.442695040888963387f
#define B1 256          // blocks in bin/scatter phase
#define BSHIFT 8        // bucket = dst >> 8 (256 nodes per bucket)
#define BNODES 256

typedef __attribute__((ext_vector_type(8))) short short8;
typedef __attribute__((ext_vector_type(4))) float f32x4;

static __device__ __forceinline__ unsigned short f2bf(float f) {
  union { float f; unsigned u; } v; v.f = f;
  unsigned r = v.u + 0x7fff + ((v.u >> 16) & 1);  // RNE
  return (unsigned short)(r >> 16);
}
static __device__ __forceinline__ float bf2f(unsigned short h) {
  union { unsigned u; float f; } v; v.u = ((unsigned)h) << 16; return v.f;
}
static __device__ __forceinline__ unsigned pkbf(float a, float b) {
  union { __hip_bfloat162 h; unsigned u; } c;
  c.h = __float22bfloat162_rn(float2{a, b});
  return c.u;
}
static __device__ __forceinline__ int rfl(int v) {
  return __builtin_amdgcn_readfirstlane(v);
}

// ---------- prep: W1T[64][1024] bf16 = transpose(W1[1024][64]) ----------
__global__ __launch_bounds__(256) void w1cvt_kernel(const float* __restrict__ W1,
                                                    unsigned short* __restrict__ w1t) {
  int i = blockIdx.x * 256 + threadIdx.x;           // 65536 total
  int c = i >> 10, k = i & 1023;
  w1t[i] = f2bf(W1[(size_t)k * F1 + c]);
}

// ---------- K1: GEMM1 MFMA (blocks 0..gB-1) ++ binhist (blocks gB..gB+255) ----------
// GEMM first in dispatch order so the long pole starts immediately; hist fills the tail.
// hist also accumulates bucket totals into btot (global atomics, R7-proven).
__global__ __launch_bounds__(256) void k1_hist_gemm(const float* __restrict__ x,
    const unsigned short* __restrict__ w1t, unsigned short* __restrict__ xw1,
    const int* __restrict__ dst, int* __restrict__ cnt, int* __restrict__ btot,
    int n, int e, int nbuck, int gB) {
  const int bid = blockIdx.x;
  const int tid = threadIdx.x;
  if (bid >= gB) {
    const int hb = bid - gB;
    __shared__ int lh[512];
    lh[tid] = 0; lh[tid + 256] = 0;
    __syncthreads();
    int chunk = (e + B1 - 1) / B1;
    int s = hb * chunk, en = min(e, s + chunk);
    for (int i = s + tid; i < en; i += 256) atomicAdd(&lh[dst[i] >> BSHIFT], 1);
    __syncthreads();
    for (int b = tid; b < nbuck; b += 256) {
      cnt[b * B1 + hb] = lh[b];
      if (lh[b]) atomicAdd(&btot[b], lh[b]);
    }
    return;
  }
  const int gb = bid;
  const int wv = tid >> 6;
  const int l = tid & 63;
  const int lr = l & 15;
  const int lg = l >> 4;
  const int rowBase = gb * 128 + wv * 32;
  int r0 = rowBase + lr, r1 = rowBase + 16 + lr;
  int r0c = r0 < n ? r0 : (n - 1);
  int r1c = r1 < n ? r1 : (n - 1);
  const float* px0 = x + (size_t)r0c * F_IN + lg * 8;
  const float* px1 = x + (size_t)r1c * F_IN + lg * 8;

  f32x4 acc00 = {0.f,0.f,0.f,0.f}, acc01 = acc00, acc02 = acc00, acc03 = acc00;
  f32x4 acc10 = acc00, acc11 = acc00, acc12 = acc00, acc13 = acc00;

#pragma unroll 2
  for (int k0 = 0; k0 < F_IN; k0 += 32) {
    float4 xa0 = *(const float4*)(px0 + k0);
    float4 xb0 = *(const float4*)(px0 + k0 + 4);
    float4 xa1 = *(const float4*)(px1 + k0);
    float4 xb1 = *(const float4*)(px1 + k0 + 4);
    union { short8 s; unsigned u[4]; } a0, a1;
    a0.u[0] = pkbf(xa0.x, xa0.y); a0.u[1] = pkbf(xa0.z, xa0.w);
    a0.u[2] = pkbf(xb0.x, xb0.y); a0.u[3] = pkbf(xb0.z, xb0.w);
    a1.u[0] = pkbf(xa1.x, xa1.y); a1.u[1] = pkbf(xa1.z, xa1.w);
    a1.u[2] = pkbf(xb1.x, xb1.y); a1.u[3] = pkbf(xb1.z, xb1.w);
    const size_t kOff = (size_t)(k0 + lg * 8);
    short8 b0 = *(const short8*)(w1t + (size_t)(0 * 16 + lr) * F_IN + kOff);
    short8 b1 = *(const short8*)(w1t + (size_t)(1 * 16 + lr) * F_IN + kOff);
    short8 b2 = *(const short8*)(w1t + (size_t)(2 * 16 + lr) * F_IN + kOff);
    short8 b3 = *(const short8*)(w1t + (size_t)(3 * 16 + lr) * F_IN + kOff);
    acc00 = __builtin_amdgcn_mfma_f32_16x16x32_bf16(a0.s, b0, acc00, 0, 0, 0);
    acc01 = __builtin_amdgcn_mfma_f32_16x16x32_bf16(a0.s, b1, acc01, 0, 0, 0);
    acc02 = __builtin_amdgcn_mfma_f32_16x16x32_bf16(a0.s, b2, acc02, 0, 0, 0);
    acc03 = __builtin_amdgcn_mfma_f32_16x16x32_bf16(a0.s, b3, acc03, 0, 0, 0);
    acc10 = __builtin_amdgcn_mfma_f32_16x16x32_bf16(a1.s, b0, acc10, 0, 0, 0);
    acc11 = __builtin_amdgcn_mfma_f32_16x16x32_bf16(a1.s, b1, acc11, 0, 0, 0);
    acc12 = __builtin_amdgcn_mfma_f32_16x16x32_bf16(a1.s, b2, acc12, 0, 0, 0);
    acc13 = __builtin_amdgcn_mfma_f32_16x16x32_bf16(a1.s, b3, acc13, 0, 0, 0);
  }

  // C/D layout: col = lane&15, row = (lane>>4)*4 + reg   [m89-verified]
#pragma unroll
  for (int r = 0; r < 4; ++r) {
    int o0 = rowBase + lg * 4 + r;
    if (o0 < n) {
      unsigned short* po = xw1 + (size_t)o0 * F1 + lr;
      po[0]  = f2bf(acc00[r]);
      po[16] = f2bf(acc01[r]);
      po[32] = f2bf(acc02[r]);
      po[48] = f2bf(acc03[r]);
    }
    int o1 = rowBase + 16 + lg * 4 + r;
    if (o1 < n) {
      unsigned short* po = xw1 + (size_t)o1 * F1 + lr;
      po[0]  = f2bf(acc10[r]);
      po[16] = f2bf(acc11[r]);
      po[32] = f2bf(acc12[r]);
      po[48] = f2bf(acc13[r]);
    }
  }
}

// ---------- K2: btot-scan (block 0) ++ scan1 (blocks 1..nbScan) ++ al1 (rest) ----------
__global__ __launch_bounds__(256) void k2_scan_al1(const int* __restrict__ in,
    int* __restrict__ excl, const int* __restrict__ btot, int* __restrict__ bstart,
    int len, int nbScan, int nbuck, int e,
    const unsigned short* __restrict__ xw1, const float* __restrict__ asrc,
    const float* __restrict__ adst, float* __restrict__ al_src,
    float* __restrict__ al_dst, int n) {
  const int bid = blockIdx.x;
  const int tid = threadIdx.x;
  if (bid == 0) {
    // exclusive scan of the nbuck (<512) bucket totals -> bstart; bstart[nbuck]=e
    __shared__ int s[512];
    int v0 = tid < nbuck ? btot[tid] : 0;
    int v1 = (tid + 256) < nbuck ? btot[tid + 256] : 0;
    s[tid] = v0; s[tid + 256] = v1;
    __syncthreads();
    for (int ofs = 1; ofs < 512; ofs <<= 1) {
      int a0 = s[tid], a1 = s[tid + 256];
      int b0 = (tid >= ofs) ? s[tid - ofs] : 0;
      int b1 = (tid + 256 >= ofs) ? s[tid + 256 - ofs] : 0;
      __syncthreads();
      s[tid] = a0 + b0; s[tid + 256] = a1 + b1;
      __syncthreads();
    }
    if (tid < nbuck) bstart[tid] = s[tid] - v0;
    if (tid + 256 < nbuck) bstart[tid + 256] = s[tid + 256] - v1;
    if (tid == 0) bstart[nbuck] = e;
    return;
  }
  if (bid <= nbScan) {
    __shared__ int s[256];
    int gid = (bid - 1) * 256 + tid;
    int v = gid < len ? in[gid] : 0;
    s[tid] = v;
    __syncthreads();
    for (int ofs = 1; ofs < 256; ofs <<= 1) {
      int t = (tid >= ofs) ? s[tid - ofs] : 0;
      __syncthreads();
      s[tid] += t;
      __syncthreads();
    }
    if (gid < len) excl[gid] = s[tid] - v;
    return;
  }
  // al1 path (scaled by LOG2E)
  int id = (bid - 1 - nbScan) * 256 + tid;
  if (id >= n * H1) return;
  int node = id >> 3, h = id & 7;
  union { short8 s; unsigned short u[8]; } rowv;
  rowv.s = *(const short8*)(xw1 + (size_t)node * F1 + h * C1);   // 16B vector load
  float s = 0.f, d = 0.f;
#pragma unroll
  for (int c = 0; c < C1; ++c) {
    float v = bf2f(rowv.u[c]);
    s += v * asrc[h * C1 + c];
    d += v * adst[h * C1 + c];
  }
  al_src[id] = s * LOG2E;
  al_dst[id] = d * LOG2E;
}

// ---------- binscatter: edges -> bucket-contiguous runs ----------
__global__ __launch_bounds__(256) void binscatter_kernel(const int* __restrict__ src,
    const int* __restrict__ dst, const int* __restrict__ cntS,
    const int* __restrict__ bstart, unsigned* __restrict__ binned, int e, int nbuck) {
  __shared__ int lcur[512];
  int tid = threadIdx.x, blk = blockIdx.x;
  for (int b = tid; b < nbuck; b += 256) lcur[b] = cntS[b * B1 + blk] + bstart[b];
  __syncthreads();
  int chunk = (e + gridDim.x - 1) / gridDim.x;
  int s = blk * chunk, en = min(e, s + chunk);
  for (int i = s + tid; i < en; i += 256) {
    int d = dst[i];
    int pos = atomicAdd(&lcur[d >> BSHIFT], 1);
    binned[pos] = ((unsigned)(d & (BNODES - 1)) << 23) | (unsigned)src[i];
  }
}

// ---------- per-bucket counting sort -> deg, off, csr ----------
__global__ __launch_bounds__(256) void bucket_csr_kernel(const unsigned* __restrict__ binned,
    const int* __restrict__ bstart, int* __restrict__ deg, int* __restrict__ off,
    int* __restrict__ csr, int e, int n, int nbuck) {
  int q = blockIdx.x, tid = threadIdx.x;
  int eBase = bstart[q];
  int eEnd = bstart[q + 1];
  __shared__ int nh[BNODES], sc[BNODES], cu[BNODES];
  nh[tid] = 0;
  __syncthreads();
  for (int i = eBase + tid; i < eEnd; i += 256) atomicAdd(&nh[binned[i] >> 23], 1);
  __syncthreads();
  int v = nh[tid];
  sc[tid] = v;
  __syncthreads();
  for (int ofs = 1; ofs < BNODES; ofs <<= 1) {
    int t = (tid >= ofs) ? sc[tid - ofs] : 0;
    __syncthreads();
    sc[tid] += t;
    __syncthreads();
  }
  int ex = sc[tid] - v;
  cu[tid] = ex;
  int node0 = q * BNODES + tid;
  if (node0 < n) { deg[node0] = v; off[node0] = eBase + ex; }
  __syncthreads();
  for (int i = eBase + tid; i < eEnd; i += 256) {
    unsigned w = binned[i];
    int pos = eBase + atomicAdd(&cu[w >> 23], 1);
    csr[pos] = (int)(w & 0x7FFFFF);
  }
}

// ---------- layer-1 aggregation: wave per node, 16 edges/batch, 2 ch/lane ----------
__global__ __launch_bounds__(256) void gat1_agg(const unsigned short* __restrict__ xw1,
    const float* __restrict__ al_src, const float* __restrict__ al_dst,
    const int* __restrict__ csr, const int* __restrict__ off, const int* __restrict__ deg,
    const float* __restrict__ b1, float* __restrict__ h1, int n) {
  const int node = rfl((int)((blockIdx.x * blockDim.x + threadIdx.x) >> 6));
  if (node >= n) return;
  const int lane = threadIdx.x & 63;
  const int half = lane >> 5;
  const int c2 = lane & 31;
  const int h = c2 >> 2;
  const int base = rfl(off[node]);
  const int cnt = rfl(deg[node]);
  const float adst = al_dst[node * H1 + h];
  const int* __restrict__ csrp = csr + base;
  const char* xwB = (const char*)xw1;
  const char* alB = (const char*)al_src;
  const int cOff = c2 << 2;
  const int hOff = h << 2;

  float acc0 = 0.f, acc1 = 0.f, l = 0.f;

#define PAIR_BODY(wv_, av_) { \
    float t = (av_) + adst; \
    float sc = fmaxf(t, NEG * t); \
    float p = __builtin_amdgcn_exp2f(sc); \
    acc0 = fmaf(p, bf2f((unsigned short)((wv_) & 0xffffu)), acc0); \
    acc1 = fmaf(p, bf2f((unsigned short)((wv_) >> 16)), acc1); \
    l += p; }

  int it = 0;
  for (; it + 16 <= cnt; it += 16) {
    int xo[8];
#pragma unroll
    for (int jp = 0; jp < 8; ++jp) {
      int s0 = rfl(csrp[it + 2 * jp]) << 7;
      int s1 = rfl(csrp[it + 2 * jp + 1]) << 7;
      xo[jp] = half ? s1 : s0;
    }
    unsigned wv[8]; float av[8];
#pragma unroll
    for (int jp = 0; jp < 8; ++jp) {
      wv[jp] = *(const unsigned*)(xwB + xo[jp] + cOff);
      av[jp] = *(const float*)(alB + (xo[jp] >> 2) + hOff);
    }
#pragma unroll
    for (int jp = 0; jp < 8; ++jp) PAIR_BODY(wv[jp], av[jp]);
  }
  for (; it + 2 <= cnt; it += 2) {
    int s0 = rfl(csrp[it]) << 7;
    int s1 = rfl(csrp[it + 1]) << 7;
    int bs = half ? s1 : s0;
    unsigned w = *(const unsigned*)(xwB + bs + cOff);
    float av = *(const float*)(alB + (bs >> 2) + hOff);
    PAIR_BODY(w, av);
  }
  {
    const bool odd = (it < cnt);
    int sA = odd ? rfl(csrp[it]) : node;
    int bs = (half ? node : sA) << 7;
    unsigned w = *(const unsigned*)(xwB + bs + cOff);
    float av = *(const float*)(alB + (bs >> 2) + hOff);
    float t = av + adst;
    float sc = fmaxf(t, NEG * t);
    float p = __builtin_amdgcn_exp2f(sc);
    if (!odd && half) p = 0.f;
    acc0 = fmaf(p, bf2f((unsigned short)(w & 0xffffu)), acc0);
    acc1 = fmaf(p, bf2f((unsigned short)(w >> 16)), acc1);
    l += p;
  }
#undef PAIR_BODY

  acc0 += __shfl_xor(acc0, 32);
  acc1 += __shfl_xor(acc1, 32);
  l    += __shfl_xor(l, 32);
  if (half == 0) {
    float inv = 1.f / (l + 1e-16f);
    float2 bv = *(const float2*)(b1 + (c2 << 1));
    float o0 = acc0 * inv + bv.x;
    float o1 = acc1 * inv + bv.y;
    o0 = o0 > 0.f ? o0 : __expf(o0) - 1.f;
    o1 = o1 > 0.f ? o1 : __expf(o1) - 1.f;
    *(float2*)(h1 + (size_t)node * F1 + (c2 << 1)) = make_float2(o0, o1);
  }
}

// ---------- GEMM2 + al2 fused: xw2 row = 40 bf16 + alS fp32 @byte80 ----------
__global__ __launch_bounds__(256) void gemm2_kernel(const float* __restrict__ h1,
    const float* __restrict__ W2, const float* __restrict__ asrc,
    const float* __restrict__ adst, unsigned short* __restrict__ xw2,
    float* __restrict__ alD2, int n) {
  __shared__ float ws[F1 * C_OUT];
  __shared__ float wsa[C_OUT], wsd[C_OUT];
  int tid = threadIdx.x;
  for (int i = tid; i < F1 * C_OUT; i += 256) ws[i] = W2[i];
  if (tid < C_OUT) { wsa[tid] = asrc[tid]; wsd[tid] = adst[tid]; }
  __syncthreads();
  int node = blockIdx.x * 256 + tid;
  if (node >= n) return;
  const float4* row4 = (const float4*)(h1 + (size_t)node * F1);
  float acc[C_OUT];
#pragma unroll
  for (int j = 0; j < C_OUT; ++j) acc[j] = 0.f;
#pragma unroll 2
  for (int k4 = 0; k4 < 16; ++k4) {
    float4 xv = row4[k4];
    const float* w0 = &ws[(4 * k4 + 0) * C_OUT];
    const float* w1 = &ws[(4 * k4 + 1) * C_OUT];
    const float* w2 = &ws[(4 * k4 + 2) * C_OUT];
    const float* w3 = &ws[(4 * k4 + 3) * C_OUT];
#pragma unroll
    for (int j = 0; j < C_OUT; j += 4) {
      float4 v0 = *(const float4*)(w0 + j);
      float4 v1 = *(const float4*)(w1 + j);
      float4 v2 = *(const float4*)(w2 + j);
      float4 v3 = *(const float4*)(w3 + j);
      acc[j + 0] += xv.x * v0.x + xv.y * v1.x + xv.z * v2.x + xv.w * v3.x;
      acc[j + 1] += xv.x * v0.y + xv.y * v1.y + xv.z * v2.y + xv.w * v3.y;
      acc[j + 2] += xv.x * v0.z + xv.y * v1.z + xv.z * v2.z + xv.w * v3.z;
      acc[j + 3] += xv.x * v0.w + xv.y * v1.w + xv.z * v2.w + xv.w * v3.w;
    }
  }
  float s = 0.f, d = 0.f;
#pragma unroll
  for (int j = 0; j < C_OUT; ++j) { s += acc[j] * wsa[j]; d += acc[j] * wsd[j]; }
  alD2[node] = d * LOG2E;
  unsigned short* orow = xw2 + (size_t)node * XW2S;
#pragma unroll
  for (int j = 0; j < C_OUT; j += 4) {
    ushort4 o;
    o.x = f2bf(acc[j + 0]); o.y = f2bf(acc[j + 1]);
    o.z = f2bf(acc[j + 2]); o.w = f2bf(acc[j + 3]);
    *(ushort4*)(orow + j) = o;
  }
  *(float*)(orow + C_OUT) = s * LOG2E;   // alS embedded at byte offset 80
}

// ---------- layer-2 aggregation + log_softmax: wave per node, 16 edges/batch ----------
__global__ __launch_bounds__(256) void gat2_agg(const unsigned short* __restrict__ xw2,
    const float* __restrict__ alD,
    const int* __restrict__ csr, const int* __restrict__ off, const int* __restrict__ deg,
    const float* __restrict__ b2, float* __restrict__ out, int n) {
  const int node = rfl((int)((blockIdx.x * blockDim.x + threadIdx.x) >> 6));
  if (node >= n) return;
  const int lane = threadIdx.x & 63;
  const int half = lane >> 5;
  const int c2 = lane & 31;
  const bool act = c2 < 20;
  const int c2r = act ? c2 : 0;
  const int base = rfl(off[node]);
  const int cnt = rfl(deg[node]);
  const float adst = alD[node];
  const int* __restrict__ csrp = csr + base;
  const char* xwB = (const char*)xw2;
  const int cOff = c2r << 2;

  float acc0 = 0.f, acc1 = 0.f, l = 0.f;

#define PAIR_BODY2(wv_, av_) { \
    float t = (av_) + adst; \
    float sc = fmaxf(t, NEG * t); \
    float p = __builtin_amdgcn_exp2f(sc); \
    acc0 = fmaf(p, bf2f((unsigned short)((wv_) & 0xffffu)), acc0); \
    acc1 = fmaf(p, bf2f((unsigned short)((wv_) >> 16)), acc1); \
    l += p; }

  int it = 0;
  for (; it + 16 <= cnt; it += 16) {
    int xo[8];
#pragma unroll
    for (int jp = 0; jp < 8; ++jp) {
      int s0 = rfl(csrp[it + 2 * jp]) << 7;     // padded row: s*128 bytes
      int s1 = rfl(csrp[it + 2 * jp + 1]) << 7;
      xo[jp] = half ? s1 : s0;
    }
    unsigned wv[8]; float av[8];
#pragma unroll
    for (int jp = 0; jp < 8; ++jp) {
      wv[jp] = *(const unsigned*)(xwB + xo[jp] + cOff);
      av[jp] = *(const float*)(xwB + xo[jp] + 80);   // alS embedded in row
    }
#pragma unroll
    for (int jp = 0; jp < 8; ++jp) PAIR_BODY2(wv[jp], av[jp]);
  }
  for (; it + 2 <= cnt; it += 2) {
    int s0 = rfl(csrp[it]) << 7;
    int s1 = rfl(csrp[it + 1]) << 7;
    int bs = half ? s1 : s0;
    unsigned w = *(const unsigned*)(xwB + bs + cOff);
    float av = *(const float*)(xwB + bs + 80);
    PAIR_BODY2(w, av);
  }
  {
    const bool odd = (it < cnt);
    int sA = odd ? rfl(csrp[it]) : node;
    int bs = (half ? node : sA) << 7;
    unsigned w = *(const unsigned*)(xwB + bs + cOff);
    float av = *(const float*)(xwB + bs + 80);
    float t = av + adst;
    float sc = fmaxf(t, NEG * t);
    float p = __builtin_amdgcn_exp2f(sc);
    if (!odd && half) p = 0.f;
    acc0 = fmaf(p, bf2f((unsigned short)(w & 0xffffu)), acc0);
    acc1 = fmaf(p, bf2f((unsigned short)(w >> 16)), acc1);
    l += p;
  }
#undef PAIR_BODY2

  acc0 += __shfl_xor(acc0, 32);
  acc1 += __shfl_xor(acc1, 32);
  l    += __shfl_xor(l, 32);

  float inv = 1.f / (l + 1e-16f);
  float v0 = -1e30f, v1 = -1e30f;
  if (act) {
    float2 bv = *(const float2*)(b2 + (c2 << 1));
    v0 = acc0 * inv + bv.x;
    v1 = acc1 * inv + bv.y;
  }
  float mx = fmaxf(v0, v1);
#pragma unroll
  for (int mask = 1; mask <= 16; mask <<= 1) mx = fmaxf(mx, __shfl_xor(mx, mask));
  float e0 = act ? __expf(v0 - mx) : 0.f;
  float e1 = act ? __expf(v1 - mx) : 0.f;
  float sum = e0 + e1;
#pragma unroll
  for (int mask = 1; mask <= 16; mask <<= 1) sum += __shfl_xor(sum, mask);
  if (half == 0 && act) {
    float ls = __logf(sum);
    *(float2*)(out + (size_t)node * C_OUT + (c2 << 1)) =
        make_float2(v0 - mx - ls, v1 - mx - ls);
  }
}

extern "C" void kernel_launch(void* const* d_in, const int* in_sizes, int n_in,
                              void* d_out, int out_size, void* d_ws, size_t ws_size,
                              hipStream_t stream) {
  const float* x   = (const float*)d_in[0];
  const int*   ei  = (const int*)d_in[1];
  const float* W1  = (const float*)d_in[2];
  const float* as1 = (const float*)d_in[3];
  const float* ad1 = (const float*)d_in[4];
  const float* b1  = (const float*)d_in[5];
  const float* W2  = (const float*)d_in[6];
  const float* as2 = (const float*)d_in[7];
  const float* ad2 = (const float*)d_in[8];
  const float* b2  = (const float*)d_in[9];
  float* out = (float*)d_out;

  const int n = in_sizes[0] / F_IN;
  const int e = in_sizes[1] / 2;
  const int* srcIdx = ei;
  const int* dstIdx = ei + e;
  const int nbuck = (n + BNODES - 1) >> BSHIFT;   // <= 512 for n <= 128k
  const int clen = nbuck * B1;                    // flat counter array length

  char* p = (char*)d_ws;
  auto take = [&](size_t bytes) {
    char* q = p;
    p += (bytes + 255) & ~(size_t)255;
    return q;
  };
  unsigned short* xw1 = (unsigned short*)take((size_t)n * F1 * 2);
  float* h1           = (float*)take((size_t)n * F1 * 4);
  unsigned short* xw2 = (unsigned short*)take((size_t)n * XW2S * 2);
  unsigned short* w1t = (unsigned short*)take((size_t)F_IN * F1 * 2);
  float* alS1 = (float*)take((size_t)n * H1 * 4);
  float* alD1 = (float*)take((size_t)n * H1 * 4);
  float* alD2 = (float*)take((size_t)n * 4);
  int* deg    = (int*)take((size_t)n * 4);
  int* offb   = (int*)take((size_t)n * 4);
  int* cnt    = (int*)take((size_t)clen * 4);
  int* cntS   = (int*)take((size_t)clen * 4);
  int* btot   = (int*)take(2048);
  int* bstart = (int*)take(2052 + 256);
  unsigned* binned = (unsigned*)take((size_t)e * 4);
  int* csr    = (int*)take((size_t)e * 4);

  dim3 b256(256);
  const int gB = (n + 127) / 128;
  const int alBlocks = (n * H1 + 255) / 256;
  int nbScan = (clen + 255) / 256;                // == nbuck

  hipMemsetAsync(btot, 0, (size_t)nbuck * 4, stream);
  w1cvt_kernel<<<dim3((F_IN * F1) / 256), b256, 0, stream>>>(W1, w1t);
  k1_hist_gemm<<<dim3(gB + B1), b256, 0, stream>>>(x, w1t, xw1, dstIdx, cnt, btot,
                                                   n, e, nbuck, gB);
  k2_scan_al1<<<dim3(1 + nbScan + alBlocks), b256, 0, stream>>>(cnt, cntS, btot,
      bstart, clen, nbScan, nbuck, e, xw1, as1, ad1, alS1, alD1, n);
  binscatter_kernel<<<dim3(B1), b256, 0, stream>>>(srcIdx, dstIdx, cntS, bstart,
                                                   binned, e, nbuck);
  bucket_csr_kernel<<<dim3(nbuck), b256, 0, stream>>>(binned, bstart, deg, offb,
                                                      csr, e, n, nbuck);

  gat1_agg<<<dim3((n + 3) / 4), b256, 0, stream>>>(xw1, alS1, alD1, csr, offb, deg, b1, h1, n);
  gemm2_kernel<<<dim3((n + 255) / 256), b256, 0, stream>>>(h1, W2, as2, ad2, xw2, alD2, n);
  gat2_agg<<<dim3((n + 3) / 4), b256, 0, stream>>>(xw2, alD2, csr, offb, deg, b2, out, n);
}

// Round 20
// 380.199 us; speedup vs baseline: 1.0666x; 1.0666x over previous
//
#include <hip/hip_runtime.h>
#include <hip/hip_bf16.h>
#include <cstdint>
#include <cstddef>

#define F_IN 1024
#define F1 64
#define H1 8
#define C1 8
#define C_OUT 40
#define XW2S 64         // padded xw2 row stride (bf16) -> 128 B lines; byte 80 holds alS fp32
#define NEG 0.2f
#define LOG2E 1.442695040888963387f
#define B1 256          // blocks in bin/scatter phase
#define BSHIFT 8        // bucket = dst >> 8 (256 nodes per bucket)
#define BNODES 256

typedef __attribute__((ext_vector_type(8))) short short8;
typedef __attribute__((ext_vector_type(4))) float f32x4;

static __device__ __forceinline__ unsigned short f2bf(float f) {
  union { float f; unsigned u; } v; v.f = f;
  unsigned r = v.u + 0x7fff + ((v.u >> 16) & 1);  // RNE
  return (unsigned short)(r >> 16);
}
static __device__ __forceinline__ float bf2f(unsigned short h) {
  union { unsigned u; float f; } v; v.u = ((unsigned)h) << 16; return v.f;
}
static __device__ __forceinline__ unsigned pkbf(float a, float b) {
  union { __hip_bfloat162 h; unsigned u; } c;
  c.h = __float22bfloat162_rn(float2{a, b});
  return c.u;
}
static __device__ __forceinline__ int rfl(int v) {
  return __builtin_amdgcn_readfirstlane(v);
}

// ---------- prep: W1T[64][1024] bf16 = transpose(W1[1024][64]) ----------
__global__ __launch_bounds__(256) void w1cvt_kernel(const float* __restrict__ W1,
                                                    unsigned short* __restrict__ w1t) {
  int i = blockIdx.x * 256 + threadIdx.x;           // 65536 total
  int c = i >> 10, k = i & 1023;
  w1t[i] = f2bf(W1[(size_t)k * F1 + c]);
}

// ---------- K1: binhist (blocks 0..255, LDS atomics only) ++ GEMM1 MFMA ----------
__global__ __launch_bounds__(256) void k1_hist_gemm(const float* __restrict__ x,
    const unsigned short* __restrict__ w1t, unsigned short* __restrict__ xw1,
    const int* __restrict__ dst, int* __restrict__ cnt, int n, int e, int nbuck) {
  const int bid = blockIdx.x;
  const int tid = threadIdx.x;
  if (bid < B1) {
    __shared__ int lh[512];
    lh[tid] = 0; lh[tid + 256] = 0;
    __syncthreads();
    int chunk = (e + B1 - 1) / B1;
    int s = bid * chunk, en = min(e, s + chunk);
    for (int i = s + tid; i < en; i += 256) atomicAdd(&lh[dst[i] >> BSHIFT], 1);
    __syncthreads();
    for (int b = tid; b < nbuck; b += 256) cnt[b * B1 + bid] = lh[b];
    return;
  }
  const int gb = bid - B1;
  const int wv = tid >> 6;
  const int l = tid & 63;
  const int lr = l & 15;
  const int lg = l >> 4;
  const int rowBase = gb * 128 + wv * 32;
  int r0 = rowBase + lr, r1 = rowBase + 16 + lr;
  int r0c = r0 < n ? r0 : (n - 1);
  int r1c = r1 < n ? r1 : (n - 1);
  const float* px0 = x + (size_t)r0c * F_IN + lg * 8;
  const float* px1 = x + (size_t)r1c * F_IN + lg * 8;

  f32x4 acc00 = {0.f,0.f,0.f,0.f}, acc01 = acc00, acc02 = acc00, acc03 = acc00;
  f32x4 acc10 = acc00, acc11 = acc00, acc12 = acc00, acc13 = acc00;

#pragma unroll 2
  for (int k0 = 0; k0 < F_IN; k0 += 32) {
    float4 xa0 = *(const float4*)(px0 + k0);
    float4 xb0 = *(const float4*)(px0 + k0 + 4);
    float4 xa1 = *(const float4*)(px1 + k0);
    float4 xb1 = *(const float4*)(px1 + k0 + 4);
    union { short8 s; unsigned u[4]; } a0, a1;
    a0.u[0] = pkbf(xa0.x, xa0.y); a0.u[1] = pkbf(xa0.z, xa0.w);
    a0.u[2] = pkbf(xb0.x, xb0.y); a0.u[3] = pkbf(xb0.z, xb0.w);
    a1.u[0] = pkbf(xa1.x, xa1.y); a1.u[1] = pkbf(xa1.z, xa1.w);
    a1.u[2] = pkbf(xb1.x, xb1.y); a1.u[3] = pkbf(xb1.z, xb1.w);
    const size_t kOff = (size_t)(k0 + lg * 8);
    short8 b0 = *(const short8*)(w1t + (size_t)(0 * 16 + lr) * F_IN + kOff);
    short8 b1 = *(const short8*)(w1t + (size_t)(1 * 16 + lr) * F_IN + kOff);
    short8 b2 = *(const short8*)(w1t + (size_t)(2 * 16 + lr) * F_IN + kOff);
    short8 b3 = *(const short8*)(w1t + (size_t)(3 * 16 + lr) * F_IN + kOff);
    acc00 = __builtin_amdgcn_mfma_f32_16x16x32_bf16(a0.s, b0, acc00, 0, 0, 0);
    acc01 = __builtin_amdgcn_mfma_f32_16x16x32_bf16(a0.s, b1, acc01, 0, 0, 0);
    acc02 = __builtin_amdgcn_mfma_f32_16x16x32_bf16(a0.s, b2, acc02, 0, 0, 0);
    acc03 = __builtin_amdgcn_mfma_f32_16x16x32_bf16(a0.s, b3, acc03, 0, 0, 0);
    acc10 = __builtin_amdgcn_mfma_f32_16x16x32_bf16(a1.s, b0, acc10, 0, 0, 0);
    acc11 = __builtin_amdgcn_mfma_f32_16x16x32_bf16(a1.s, b1, acc11, 0, 0, 0);
    acc12 = __builtin_amdgcn_mfma_f32_16x16x32_bf16(a1.s, b2, acc12, 0, 0, 0);
    acc13 = __builtin_amdgcn_mfma_f32_16x16x32_bf16(a1.s, b3, acc13, 0, 0, 0);
  }

  // C/D layout: col = lane&15, row = (lane>>4)*4 + reg   [m89-verified]
#pragma unroll
  for (int r = 0; r < 4; ++r) {
    int o0 = rowBase + lg * 4 + r;
    if (o0 < n) {
      unsigned short* po = xw1 + (size_t)o0 * F1 + lr;
      po[0]  = f2bf(acc00[r]);
      po[16] = f2bf(acc01[r]);
      po[32] = f2bf(acc02[r]);
      po[48] = f2bf(acc03[r]);
    }
    int o1 = rowBase + 16 + lg * 4 + r;
    if (o1 < n) {
      unsigned short* po = xw1 + (size_t)o1 * F1 + lr;
      po[0]  = f2bf(acc10[r]);
      po[16] = f2bf(acc11[r]);
      po[32] = f2bf(acc12[r]);
      po[48] = f2bf(acc13[r]);
    }
  }
}

// ---------- K2: scan1 (blocks 0..nbScan-1) ++ al1 (blocks nbScan..) ----------
__global__ __launch_bounds__(256) void k2_scan_al1(const int* __restrict__ in,
    int* __restrict__ excl, int* __restrict__ bsum, int len, int nbScan,
    const unsigned short* __restrict__ xw1, const float* __restrict__ asrc,
    const float* __restrict__ adst, float* __restrict__ al_src,
    float* __restrict__ al_dst, int n) {
  const int bid = blockIdx.x;
  const int tid = threadIdx.x;
  if (bid < nbScan) {
    __shared__ int s[256];
    int gid = bid * 256 + tid;
    int v = gid < len ? in[gid] : 0;
    s[tid] = v;
    __syncthreads();
    for (int ofs = 1; ofs < 256; ofs <<= 1) {
      int t = (tid >= ofs) ? s[tid - ofs] : 0;
      __syncthreads();
      s[tid] += t;
      __syncthreads();
    }
    if (gid < len) excl[gid] = s[tid] - v;
    if (tid == 255) bsum[bid] = s[255];
    return;
  }
  // al1 path (scaled by LOG2E)
  int id = (bid - nbScan) * 256 + tid;
  if (id >= n * H1) return;
  int node = id >> 3, h = id & 7;
  union { short8 s; unsigned short u[8]; } rowv;
  rowv.s = *(const short8*)(xw1 + (size_t)node * F1 + h * C1);   // 16B vector load
  float s = 0.f, d = 0.f;
#pragma unroll
  for (int c = 0; c < C1; ++c) {
    float v = bf2f(rowv.u[c]);
    s += v * asrc[h * C1 + c];
    d += v * adst[h * C1 + c];
  }
  al_src[id] = s * LOG2E;
  al_dst[id] = d * LOG2E;
}

__global__ __launch_bounds__(1024) void scan2_kernel(int* __restrict__ bsum, int nb) {
  __shared__ int s[1024];
  int tid = threadIdx.x;
  int v = tid < nb ? bsum[tid] : 0;
  s[tid] = v;
  __syncthreads();
  for (int ofs = 1; ofs < 1024; ofs <<= 1) {
    int t = (tid >= ofs) ? s[tid - ofs] : 0;
    __syncthreads();
    s[tid] += t;
    __syncthreads();
  }
  if (tid < nb) bsum[tid] = s[tid] - v;  // exclusive
}

// ---------- binscatter: edges -> bucket-contiguous runs (4x batched loads) ----------
__global__ __launch_bounds__(256) void binscatter_kernel(const int* __restrict__ src,
    const int* __restrict__ dst, const int* __restrict__ cntS,
    const int* __restrict__ bsum, unsigned* __restrict__ binned, int e, int nbuck) {
  __shared__ int lcur[512];
  int tid = threadIdx.x, blk = blockIdx.x;
  for (int b = tid; b < nbuck; b += 256) lcur[b] = cntS[b * B1 + blk] + bsum[b];
  __syncthreads();
  int chunk = (e + gridDim.x - 1) / gridDim.x;
  int s = blk * chunk, en = min(e, s + chunk);
  int i = s + tid;
  for (; i + 768 < en; i += 1024) {
    int d0 = dst[i], d1 = dst[i + 256], d2 = dst[i + 512], d3 = dst[i + 768];
    int s0 = src[i], s1 = src[i + 256], s2 = src[i + 512], s3 = src[i + 768];
    int p0 = atomicAdd(&lcur[d0 >> BSHIFT], 1);
    int p1 = atomicAdd(&lcur[d1 >> BSHIFT], 1);
    int p2 = atomicAdd(&lcur[d2 >> BSHIFT], 1);
    int p3 = atomicAdd(&lcur[d3 >> BSHIFT], 1);
    binned[p0] = ((unsigned)(d0 & (BNODES - 1)) << 23) | (unsigned)s0;
    binned[p1] = ((unsigned)(d1 & (BNODES - 1)) << 23) | (unsigned)s1;
    binned[p2] = ((unsigned)(d2 & (BNODES - 1)) << 23) | (unsigned)s2;
    binned[p3] = ((unsigned)(d3 & (BNODES - 1)) << 23) | (unsigned)s3;
  }
  for (; i < en; i += 256) {
    int d = dst[i];
    int pos = atomicAdd(&lcur[d >> BSHIFT], 1);
    binned[pos] = ((unsigned)(d & (BNODES - 1)) << 23) | (unsigned)src[i];
  }
}

// ---------- per-bucket counting sort -> deg, off, csr ----------
__global__ __launch_bounds__(256) void bucket_csr_kernel(const unsigned* __restrict__ binned,
    const int* __restrict__ bsum, int* __restrict__ deg, int* __restrict__ off,
    int* __restrict__ csr, int e, int n, int nbuck) {
  int q = blockIdx.x, tid = threadIdx.x;
  int eBase = bsum[q];
  int eEnd = (q + 1 < nbuck) ? bsum[q + 1] : e;
  __shared__ int nh[BNODES], sc[BNODES], cu[BNODES];
  nh[tid] = 0;
  __syncthreads();
  for (int i = eBase + tid; i < eEnd; i += 256) atomicAdd(&nh[binned[i] >> 23], 1);
  __syncthreads();
  int v = nh[tid];
  sc[tid] = v;
  __syncthreads();
  for (int ofs = 1; ofs < BNODES; ofs <<= 1) {
    int t = (tid >= ofs) ? sc[tid - ofs] : 0;
    __syncthreads();
    sc[tid] += t;
    __syncthreads();
  }
  int ex = sc[tid] - v;
  cu[tid] = ex;
  int node0 = q * BNODES + tid;
  if (node0 < n) { deg[node0] = v; off[node0] = eBase + ex; }
  __syncthreads();
  for (int i = eBase + tid; i < eEnd; i += 256) {
    unsigned w = binned[i];
    int pos = eBase + atomicAdd(&cu[w >> 23], 1);
    csr[pos] = (int)(w & 0x7FFFFF);
  }
}

// ---------- layer-1 aggregation: wave per node, 16 edges/batch; h1 out bf16 ----------
__global__ __launch_bounds__(256) void gat1_agg(const unsigned short* __restrict__ xw1,
    const float* __restrict__ al_src, const float* __restrict__ al_dst,
    const int* __restrict__ csr, const int* __restrict__ off, const int* __restrict__ deg,
    const float* __restrict__ b1, unsigned short* __restrict__ h1, int n) {
  const int node = rfl((int)((blockIdx.x * blockDim.x + threadIdx.x) >> 6));
  if (node >= n) return;
  const int lane = threadIdx.x & 63;
  const int half = lane >> 5;
  const int c2 = lane & 31;
  const int h = c2 >> 2;
  const int base = rfl(off[node]);
  const int cnt = rfl(deg[node]);
  const float adst = al_dst[node * H1 + h];
  const int* __restrict__ csrp = csr + base;
  const char* xwB = (const char*)xw1;
  const char* alB = (const char*)al_src;
  const int cOff = c2 << 2;
  const int hOff = h << 2;

  float acc0 = 0.f, acc1 = 0.f, l = 0.f;

#define PAIR_BODY(wv_, av_) { \
    float t = (av_) + adst; \
    float sc = fmaxf(t, NEG * t); \
    float p = __builtin_amdgcn_exp2f(sc); \
    acc0 = fmaf(p, bf2f((unsigned short)((wv_) & 0xffffu)), acc0); \
    acc1 = fmaf(p, bf2f((unsigned short)((wv_) >> 16)), acc1); \
    l += p; }

  int it = 0;
  for (; it + 16 <= cnt; it += 16) {
    int xo[8];
#pragma unroll
    for (int jp = 0; jp < 8; ++jp) {
      int s0 = rfl(csrp[it + 2 * jp]) << 7;
      int s1 = rfl(csrp[it + 2 * jp + 1]) << 7;
      xo[jp] = half ? s1 : s0;
    }
    unsigned wv[8]; float av[8];
#pragma unroll
    for (int jp = 0; jp < 8; ++jp) {
      wv[jp] = *(const unsigned*)(xwB + xo[jp] + cOff);
      av[jp] = *(const float*)(alB + (xo[jp] >> 2) + hOff);
    }
#pragma unroll
    for (int jp = 0; jp < 8; ++jp) PAIR_BODY(wv[jp], av[jp]);
  }
  for (; it + 2 <= cnt; it += 2) {
    int s0 = rfl(csrp[it]) << 7;
    int s1 = rfl(csrp[it + 1]) << 7;
    int bs = half ? s1 : s0;
    unsigned w = *(const unsigned*)(xwB + bs + cOff);
    float av = *(const float*)(alB + (bs >> 2) + hOff);
    PAIR_BODY(w, av);
  }
  {
    const bool odd = (it < cnt);
    int sA = odd ? rfl(csrp[it]) : node;
    int bs = (half ? node : sA) << 7;
    unsigned w = *(const unsigned*)(xwB + bs + cOff);
    float av = *(const float*)(alB + (bs >> 2) + hOff);
    float t = av + adst;
    float sc = fmaxf(t, NEG * t);
    float p = __builtin_amdgcn_exp2f(sc);
    if (!odd && half) p = 0.f;
    acc0 = fmaf(p, bf2f((unsigned short)(w & 0xffffu)), acc0);
    acc1 = fmaf(p, bf2f((unsigned short)(w >> 16)), acc1);
    l += p;
  }
#undef PAIR_BODY

  acc0 += __shfl_xor(acc0, 32);
  acc1 += __shfl_xor(acc1, 32);
  l    += __shfl_xor(l, 32);
  if (half == 0) {
    float inv = 1.f / (l + 1e-16f);
    float2 bv = *(const float2*)(b1 + (c2 << 1));
    float o0 = acc0 * inv + bv.x;
    float o1 = acc1 * inv + bv.y;
    o0 = o0 > 0.f ? o0 : __expf(o0) - 1.f;   // ELU
    o1 = o1 > 0.f ? o1 : __expf(o1) - 1.f;
    *(unsigned*)(h1 + (size_t)node * F1 + (c2 << 1)) = pkbf(o0, o1);
  }
}

// ---------- GEMM2 + al2 fused: h1 bf16 in; xw2 row = 40 bf16 + alS fp32 @byte80 ----------
__global__ __launch_bounds__(256) void gemm2_kernel(const unsigned short* __restrict__ h1,
    const float* __restrict__ W2, const float* __restrict__ asrc,
    const float* __restrict__ adst, unsigned short* __restrict__ xw2,
    float* __restrict__ alD2, int n) {
  __shared__ float ws[F1 * C_OUT];
  __shared__ float wsa[C_OUT], wsd[C_OUT];
  int tid = threadIdx.x;
  for (int i = tid; i < F1 * C_OUT; i += 256) ws[i] = W2[i];
  if (tid < C_OUT) { wsa[tid] = asrc[tid]; wsd[tid] = adst[tid]; }
  __syncthreads();
  int node = blockIdx.x * 256 + tid;
  if (node >= n) return;
  const short8* row8 = (const short8*)(h1 + (size_t)node * F1);
  float acc[C_OUT];
#pragma unroll
  for (int j = 0; j < C_OUT; ++j) acc[j] = 0.f;
#pragma unroll 2
  for (int k8 = 0; k8 < 8; ++k8) {
    union { short8 s; unsigned short u[8]; } xv;
    xv.s = row8[k8];
#pragma unroll
    for (int kk = 0; kk < 8; kk += 4) {
      float x0 = bf2f(xv.u[kk + 0]);
      float x1 = bf2f(xv.u[kk + 1]);
      float x2 = bf2f(xv.u[kk + 2]);
      float x3 = bf2f(xv.u[kk + 3]);
      const float* w0 = &ws[(8 * k8 + kk + 0) * C_OUT];
      const float* w1 = &ws[(8 * k8 + kk + 1) * C_OUT];
      const float* w2 = &ws[(8 * k8 + kk + 2) * C_OUT];
      const float* w3 = &ws[(8 * k8 + kk + 3) * C_OUT];
#pragma unroll
      for (int j = 0; j < C_OUT; j += 4) {
        float4 v0 = *(const float4*)(w0 + j);
        float4 v1 = *(const float4*)(w1 + j);
        float4 v2 = *(const float4*)(w2 + j);
        float4 v3 = *(const float4*)(w3 + j);
        acc[j + 0] += x0 * v0.x + x1 * v1.x + x2 * v2.x + x3 * v3.x;
        acc[j + 1] += x0 * v0.y + x1 * v1.y + x2 * v2.y + x3 * v3.y;
        acc[j + 2] += x0 * v0.z + x1 * v1.z + x2 * v2.z + x3 * v3.z;
        acc[j + 3] += x0 * v0.w + x1 * v1.w + x2 * v2.w + x3 * v3.w;
      }
    }
  }
  float s = 0.f, d = 0.f;
#pragma unroll
  for (int j = 0; j < C_OUT; ++j) { s += acc[j] * wsa[j]; d += acc[j] * wsd[j]; }
  alD2[node] = d * LOG2E;
  unsigned short* orow = xw2 + (size_t)node * XW2S;
#pragma unroll
  for (int j = 0; j < C_OUT; j += 4) {
    ushort4 o;
    o.x = f2bf(acc[j + 0]); o.y = f2bf(acc[j + 1]);
    o.z = f2bf(acc[j + 2]); o.w = f2bf(acc[j + 3]);
    *(ushort4*)(orow + j) = o;
  }
  *(float*)(orow + C_OUT) = s * LOG2E;   // alS embedded at byte offset 80
}

// ---------- layer-2 aggregation + log_softmax: wave per node, 16 edges/batch ----------
__global__ __launch_bounds__(256) void gat2_agg(const unsigned short* __restrict__ xw2,
    const float* __restrict__ alD,
    const int* __restrict__ csr, const int* __restrict__ off, const int* __restrict__ deg,
    const float* __restrict__ b2, float* __restrict__ out, int n) {
  const int node = rfl((int)((blockIdx.x * blockDim.x + threadIdx.x) >> 6));
  if (node >= n) return;
  const int lane = threadIdx.x & 63;
  const int half = lane >> 5;
  const int c2 = lane & 31;
  const bool act = c2 < 20;
  const int c2r = act ? c2 : 0;
  const int base = rfl(off[node]);
  const int cnt = rfl(deg[node]);
  const float adst = alD[node];
  const int* __restrict__ csrp = csr + base;
  const char* xwB = (const char*)xw2;
  const int cOff = c2r << 2;

  float acc0 = 0.f, acc1 = 0.f, l = 0.f;

#define PAIR_BODY2(wv_, av_) { \
    float t = (av_) + adst; \
    float sc = fmaxf(t, NEG * t); \
    float p = __builtin_amdgcn_exp2f(sc); \
    acc0 = fmaf(p, bf2f((unsigned short)((wv_) & 0xffffu)), acc0); \
    acc1 = fmaf(p, bf2f((unsigned short)((wv_) >> 16)), acc1); \
    l += p; }

  int it = 0;
  for (; it + 16 <= cnt; it += 16) {
    int xo[8];
#pragma unroll
    for (int jp = 0; jp < 8; ++jp) {
      int s0 = rfl(csrp[it + 2 * jp]) << 7;     // padded row: s*128 bytes
      int s1 = rfl(csrp[it + 2 * jp + 1]) << 7;
      xo[jp] = half ? s1 : s0;
    }
    unsigned wv[8]; float av[8];
#pragma unroll
    for (int jp = 0; jp < 8; ++jp) {
      wv[jp] = *(const unsigned*)(xwB + xo[jp] + cOff);
      av[jp] = *(const float*)(xwB + xo[jp] + 80);   // alS embedded in row
    }
#pragma unroll
    for (int jp = 0; jp < 8; ++jp) PAIR_BODY2(wv[jp], av[jp]);
  }
  for (; it + 2 <= cnt; it += 2) {
    int s0 = rfl(csrp[it]) << 7;
    int s1 = rfl(csrp[it + 1]) << 7;
    int bs = half ? s1 : s0;
    unsigned w = *(const unsigned*)(xwB + bs + cOff);
    float av = *(const float*)(xwB + bs + 80);
    PAIR_BODY2(w, av);
  }
  {
    const bool odd = (it < cnt);
    int sA = odd ? rfl(csrp[it]) : node;
    int bs = (half ? node : sA) << 7;
    unsigned w = *(const unsigned*)(xwB + bs + cOff);
    float av = *(const float*)(xwB + bs + 80);
    float t = av + adst;
    float sc = fmaxf(t, NEG * t);
    float p = __builtin_amdgcn_exp2f(sc);
    if (!odd && half) p = 0.f;
    acc0 = fmaf(p, bf2f((unsigned short)(w & 0xffffu)), acc0);
    acc1 = fmaf(p, bf2f((unsigned short)(w >> 16)), acc1);
    l += p;
  }
#undef PAIR_BODY2

  acc0 += __shfl_xor(acc0, 32);
  acc1 += __shfl_xor(acc1, 32);
  l    += __shfl_xor(l, 32);

  float inv = 1.f / (l + 1e-16f);
  float v0 = -1e30f, v1 = -1e30f;
  if (act) {
    float2 bv = *(const float2*)(b2 + (c2 << 1));
    v0 = acc0 * inv + bv.x;
    v1 = acc1 * inv + bv.y;
  }
  float mx = fmaxf(v0, v1);
#pragma unroll
  for (int mask = 1; mask <= 16; mask <<= 1) mx = fmaxf(mx, __shfl_xor(mx, mask));
  float e0 = act ? __expf(v0 - mx) : 0.f;
  float e1 = act ? __expf(v1 - mx) : 0.f;
  float sum = e0 + e1;
#pragma unroll
  for (int mask = 1; mask <= 16; mask <<= 1) sum += __shfl_xor(sum, mask);
  if (half == 0 && act) {
    float ls = __logf(sum);
    *(float2*)(out + (size_t)node * C_OUT + (c2 << 1)) =
        make_float2(v0 - mx - ls, v1 - mx - ls);
  }
}

extern "C" void kernel_launch(void* const* d_in, const int* in_sizes, int n_in,
                              void* d_out, int out_size, void* d_ws, size_t ws_size,
                              hipStream_t stream) {
  const float* x   = (const float*)d_in[0];
  const int*   ei  = (const int*)d_in[1];
  const float* W1  = (const float*)d_in[2];
  const float* as1 = (const float*)d_in[3];
  const float* ad1 = (const float*)d_in[4];
  const float* b1  = (const float*)d_in[5];
  const float* W2  = (const float*)d_in[6];
  const float* as2 = (const float*)d_in[7];
  const float* ad2 = (const float*)d_in[8];
  const float* b2  = (const float*)d_in[9];
  float* out = (float*)d_out;

  const int n = in_sizes[0] / F_IN;
  const int e = in_sizes[1] / 2;
  const int* srcIdx = ei;
  const int* dstIdx = ei + e;
  const int nbuck = (n + BNODES - 1) >> BSHIFT;   // <= 512 for n <= 128k
  const int clen = nbuck * B1;                    // flat counter array length

  char* p = (char*)d_ws;
  auto take = [&](size_t bytes) {
    char* q = p;
    p += (bytes + 255) & ~(size_t)255;
    return q;
  };
  unsigned short* xw1 = (unsigned short*)take((size_t)n * F1 * 2);
  unsigned short* h1  = (unsigned short*)take((size_t)n * F1 * 2);
  unsigned short* xw2 = (unsigned short*)take((size_t)n * XW2S * 2);
  unsigned short* w1t = (unsigned short*)take((size_t)F_IN * F1 * 2);
  float* alS1 = (float*)take((size_t)n * H1 * 4);
  float* alD1 = (float*)take((size_t)n * H1 * 4);
  float* alD2 = (float*)take((size_t)n * 4);
  int* deg  = (int*)take((size_t)n * 4);
  int* offb = (int*)take((size_t)n * 4);
  int* cnt  = (int*)take((size_t)clen * 4);
  int* cntS = (int*)take((size_t)clen * 4);
  int* bsum = (int*)take(4096);
  unsigned* binned = (unsigned*)take((size_t)e * 4);
  int* csr  = (int*)take((size_t)e * 4);

  dim3 b256(256);
  const int gB = (n + 127) / 128;
  const int alBlocks = (n * H1 + 255) / 256;
  int nbScan = (clen + 255) / 256;                // == nbuck

  w1cvt_kernel<<<dim3((F_IN * F1) / 256), b256, 0, stream>>>(W1, w1t);
  k1_hist_gemm<<<dim3(B1 + gB), b256, 0, stream>>>(x, w1t, xw1, dstIdx, cnt, n, e, nbuck);
  k2_scan_al1<<<dim3(nbScan + alBlocks), b256, 0, stream>>>(cnt, cntS, bsum, clen,
      nbScan, xw1, as1, ad1, alS1, alD1, n);
  scan2_kernel<<<dim3(1), dim3(1024), 0, stream>>>(bsum, nbScan);
  binscatter_kernel<<<dim3(B1), b256, 0, stream>>>(srcIdx, dstIdx, cntS, bsum, binned, e, nbuck);
  bucket_csr_kernel<<<dim3(nbuck), b256, 0, stream>>>(binned, bsum, deg, offb, csr, e, n, nbuck);

  gat1_agg<<<dim3((n + 3) / 4), b256, 0, stream>>>(xw1, alS1, alD1, csr, offb, deg, b1, h1, n);
  gemm2_kernel<<<dim3((n + 255) / 256), b256, 0, stream>>>(h1, W2, as2, ad2, xw2, alD2, n);
  gat2_agg<<<dim3((n + 3) / 4), b256, 0, stream>>>(xw2, alD2, csr, offb, deg, b2, out, n);
}